// Round 5
// baseline (1838.624 us; speedup 1.0000x reference)
//
#include <hip/hip_runtime.h>
#include <cstdint>

#define N_NODES 200000
#define DIM 256
#define NNZ 6400000

#define NB 782            // coarse buckets: row >> 8
#define BUCKET_CAP 17408  // 16384 expected + 8 sigma (sigma=128)
#define CHUNK 16384       // edges per block in bucket_scatter
#define TILE_SPLIT 100000 // source-node tile boundary (proj tile ~100 MB, L3-fits)

using f16 = _Float16;
typedef __attribute__((ext_vector_type(8))) _Float16 f16x8;
typedef __attribute__((ext_vector_type(4))) float f32x4;

// ---------------- init bucket cursors ----------------
__global__ void init_cursor(int* __restrict__ cursor) {
    int i = blockIdx.x * 256 + threadIdx.x;
    if (i < NB) cursor[i] = i * BUCKET_CAP;
}

// ---------------- pass A: coarse bucket scatter ----------------
// tmp record: lo32 = (col*2+adj) | (fine<<19) where fine = rowlocal*2 + tilebit (9 bits)
// hi32 = f32 bits of val
__global__ __launch_bounds__(256) void bucket_scatter(
    const int* __restrict__ rows0, const int* __restrict__ cols0, const float* __restrict__ vals0,
    const int* __restrict__ rows1, const int* __restrict__ cols1, const float* __restrict__ vals1,
    int* __restrict__ bucket_cursor, unsigned long long* __restrict__ tmp) {
    __shared__ int hist[NB];
    __shared__ int base[NB];
    const int t = threadIdx.x;
    const long e0 = (long)blockIdx.x * CHUNK;
    const int nE = (int)min((long)CHUNK, (long)(2 * NNZ) - e0);

    for (int i = t; i < NB; i += 256) hist[i] = 0;
    __syncthreads();

    for (int i = t; i < nE; i += 256) {
        long e = e0 + i;
        int r = (e < NNZ) ? rows0[e] : rows1[e - NNZ];
        atomicAdd(&hist[r >> 8], 1);
    }
    __syncthreads();

    for (int i = t; i < NB; i += 256) {
        int c = hist[i];
        base[i] = c ? atomicAdd(&bucket_cursor[i], c) : 0;
        hist[i] = 0;
    }
    __syncthreads();

    for (int i = t; i < nE; i += 256) {
        long e = e0 + i;
        int r, c;
        float v;
        unsigned adj;
        if (e < NNZ) {
            r = rows0[e]; c = cols0[e]; v = vals0[e]; adj = 0u;
        } else {
            long e1 = e - NNZ;
            r = rows1[e1]; c = cols1[e1]; v = vals1[e1]; adj = 1u;
        }
        int b = r >> 8;
        int pos = base[b] + atomicAdd(&hist[b], 1);
        if (pos < (b + 1) * BUCKET_CAP) {  // overflow guard (P ~ 1e-12)
            unsigned fine = (unsigned)(r & 255) * 2u + (c >= TILE_SPLIT ? 1u : 0u);
            unsigned lo = ((unsigned)c * 2u + adj) | (fine << 19);
            tmp[pos] = (unsigned long long)lo | ((unsigned long long)__float_as_uint(v) << 32);
        }
    }
}

// ---------------- pass B: scan bucket counts ----------------
__global__ void bucket_scan(const int* __restrict__ bucket_cursor, int* __restrict__ bucket_base) {
    __shared__ int cnt[NB + 1];
    int t = threadIdx.x;
    for (int i = t; i < NB; i += 256) {
        int c = bucket_cursor[i] - i * BUCKET_CAP;
        cnt[i] = (c > BUCKET_CAP) ? BUCKET_CAP : c;
    }
    __syncthreads();
    if (t == 0) {
        int run = 0;
        for (int i = 0; i < NB; i++) {
            int c = cnt[i];
            cnt[i] = run;
            run += c;
        }
        cnt[NB] = run;
    }
    __syncthreads();
    for (int i = t; i <= NB; i += 256) bucket_base[i] = cnt[i];
}

// ---------------- pass C: per-bucket fine sort (512 bins: row-local x tile) ----------------
__global__ __launch_bounds__(256) void bucket_sort(
    const unsigned long long* __restrict__ tmp, const int* __restrict__ bucket_cursor,
    const int* __restrict__ bucket_base, unsigned long long* __restrict__ colval,
    int* __restrict__ row_start2) {
    __shared__ int hist[512];
    __shared__ int offs[512];
    __shared__ int psc[256];
    const int b = blockIdx.x;
    const int t = threadIdx.x;
    int cnt = bucket_cursor[b] - b * BUCKET_CAP;
    if (cnt > BUCKET_CAP) cnt = BUCKET_CAP;
    const int gbase = bucket_base[b];
    const long tbase = (long)b * BUCKET_CAP;

    hist[t] = 0;
    hist[t + 256] = 0;
    __syncthreads();
    for (int i = t; i < cnt; i += 256) {
        unsigned lo = (unsigned)tmp[tbase + i];
        atomicAdd(&hist[(lo >> 19) & 511], 1);
    }
    __syncthreads();

    int s0 = hist[2 * t], s1 = hist[2 * t + 1];
    int s = s0 + s1;
    psc[t] = s;
    __syncthreads();
    for (int off = 1; off < 256; off <<= 1) {
        int v = (t >= off) ? psc[t - off] : 0;
        __syncthreads();
        psc[t] += v;
        __syncthreads();
    }
    int excl = psc[t] - s;  // exclusive over bin pairs
    offs[2 * t] = excl;
    offs[2 * t + 1] = excl + s0;

    int row = b * 256 + t;
    if (row < N_NODES) {
        row_start2[2 * row] = gbase + excl;
        row_start2[2 * row + 1] = gbase + excl + s0;
    }
    if (b == 0 && t == 0) row_start2[2 * N_NODES] = bucket_base[NB];
    hist[t] = 0;
    hist[t + 256] = 0;
    __syncthreads();

    for (int i = t; i < cnt; i += 256) {
        unsigned long long v = tmp[tbase + i];
        unsigned lo = (unsigned)v;
        int bin = (lo >> 19) & 511;
        int pos = gbase + offs[bin] + atomicAdd(&hist[bin], 1);
        colval[pos] = v & 0xFFFFFFFF0007FFFFULL;  // strip fine bits
    }
}

// ---------------- pack W0|W1 into per-lane MFMA B-fragments ----------------
__global__ void wpack_kernel(const float* __restrict__ w0, const float* __restrict__ w1,
                             f16* __restrict__ bpack) {
    int idx = blockIdx.x * 256 + threadIdx.x;  // 16384 threads
    int lane = idx & 63;
    int ct = (idx >> 6) & 31;
    int kstep = idx >> 11;
    int col = ct * 16 + (lane & 15);
    int k0 = kstep * 32 + (lane >> 4) * 8;
    const float* w = (col < 256) ? w0 : w1;
    int c = col & 255;
    union { f16 h[8]; uint4 u; } pk;
#pragma unroll
    for (int j = 0; j < 8; j++) pk.h[j] = (f16)w[(k0 + j) * 256 + c];
    reinterpret_cast<uint4*>(bpack)[idx] = pk.u;
}

// ---------------- MFMA GEMM: proj[node][512] = f16(X @ [W0|W1]) ----------------
__global__ __launch_bounds__(256) void gemm_mfma(const float* __restrict__ x,
                                                 const f16* __restrict__ bpack,
                                                 f16* __restrict__ proj) {
    __shared__ float4 xs4[64 * 64];  // 64 KB
    const int t = threadIdx.x;
    const long r0 = (long)blockIdx.x * 64;
    const float4* xg = reinterpret_cast<const float4*>(x + r0 * 256);
#pragma unroll
    for (int i = 0; i < 16; i++) {
        int idx = t + i * 256;
        int row = idx >> 6, g = idx & 63;
        xs4[row * 64 + (g ^ (row & 7))] = xg[idx];
    }
    __syncthreads();

    const int w = t >> 6, l = t & 63;
    const int r = l & 15, q = l >> 4;
    const int lrow = w * 16 + r;
    const int s = r & 7;

    for (int half = 0; half < 2; half++) {
        f32x4 acc[16];
#pragma unroll
        for (int ct = 0; ct < 16; ct++) acc[ct] = (f32x4){0.f, 0.f, 0.f, 0.f};

        for (int kstep = 0; kstep < 8; kstep++) {
            int g0 = kstep * 8 + q * 2;
            float4 a0 = xs4[lrow * 64 + (g0 ^ s)];
            float4 a1 = xs4[lrow * 64 + ((g0 + 1) ^ s)];
            f16x8 af;
            af[0] = (f16)a0.x; af[1] = (f16)a0.y; af[2] = (f16)a0.z; af[3] = (f16)a0.w;
            af[4] = (f16)a1.x; af[5] = (f16)a1.y; af[6] = (f16)a1.z; af[7] = (f16)a1.w;
            const f16x8* bp =
                reinterpret_cast<const f16x8*>(bpack) + ((kstep * 32 + half * 16) * 64 + l);
#pragma unroll
            for (int ct = 0; ct < 16; ct++) {
                f16x8 bf = bp[ct * 64];
                acc[ct] = __builtin_amdgcn_mfma_f32_16x16x32_f16(af, bf, acc[ct], 0, 0, 0);
            }
        }
#pragma unroll
        for (int ct = 0; ct < 16; ct++) {
            int col = (half * 16 + ct) * 16 + r;
#pragma unroll
            for (int i = 0; i < 4; i++) {
                long row = r0 + w * 16 + q * 4 + i;
                proj[row * 512 + col] = (f16)acc[ct][i];
            }
        }
    }
}

// ---------------- SpMM pass (source-node tiled) + bias/tanh ----------------
// pass 0: acc = bias + tile0 edges -> out (fp32 partial)
// pass 1: acc = out + tile1 edges -> tanh -> out
template <int PASS>
__global__ __launch_bounds__(256) void spmm_pass(const f16* __restrict__ proj,
                                                 const unsigned long long* __restrict__ colval,
                                                 const int* __restrict__ row_start2,
                                                 const float* __restrict__ bias,
                                                 float* __restrict__ out) {
    const int rnode = blockIdx.x;
    const int t = threadIdx.x;
    __shared__ unsigned long long se[256];

    int beg = row_start2[2 * rnode + PASS];
    const int end = row_start2[2 * rnode + PASS + 1];
    float acc;
    if (PASS == 0)
        acc = bias[t];
    else
        acc = __builtin_nontemporal_load(&out[(long)rnode * 256 + t]);

    while (beg < end) {
        int chunk = min(256, end - beg);
        __syncthreads();
        if (t < chunk) se[t] = __builtin_nontemporal_load(&colval[beg + t]);
        __syncthreads();
        int j = 0;
        for (; j + 8 <= chunk; j += 8) {
#pragma unroll
            for (int jj = 0; jj < 8; jj++) {
                unsigned long long e = se[j + jj];
                float pv = (float)proj[((long)(unsigned)e << 8) + t];
                acc = fmaf(__uint_as_float((unsigned)(e >> 32)), pv, acc);
            }
        }
        for (; j < chunk; j++) {
            unsigned long long e = se[j];
            acc = fmaf(__uint_as_float((unsigned)(e >> 32)),
                       (float)proj[((long)(unsigned)e << 8) + t], acc);
        }
        beg += chunk;
    }
    float res = (PASS == 0) ? acc : tanhf(acc);
    __builtin_nontemporal_store(res, &out[(long)rnode * 256 + t]);
}

extern "C" void kernel_launch(void* const* d_in, const int* in_sizes, int n_in,
                              void* d_out, int out_size, void* d_ws, size_t ws_size,
                              hipStream_t stream) {
    const float* x = (const float*)d_in[0];
    const float* w0 = (const float*)d_in[1];
    const float* w1 = (const float*)d_in[2];
    const float* bias = (const float*)d_in[3];
    const float* vals0 = (const float*)d_in[4];
    const float* vals1 = (const float*)d_in[5];
    const int* rows0 = (const int*)d_in[6];
    const int* cols0 = (const int*)d_in[7];
    const int* rows1 = (const int*)d_in[8];
    const int* cols1 = (const int*)d_in[9];
    float* out = (float*)d_out;

    char* ws = (char*)d_ws;
    size_t off = 0;
    auto alloc = [&](size_t bytes) -> void* {
        void* p = ws + off;
        off += (bytes + 255) & ~(size_t)255;
        return p;
    };
    unsigned long long* colval =
        (unsigned long long*)alloc((size_t)2 * NNZ * sizeof(unsigned long long));  // 102.4 MB
    // proj (205 MB) aliases tmp (109 MB): tmp is dead before gemm_mfma runs
    char* shared_region = (char*)alloc((size_t)N_NODES * 512 * sizeof(f16));       // 204.8 MB
    f16* proj = (f16*)shared_region;
    unsigned long long* tmp = (unsigned long long*)shared_region;
    int* row_start2 = (int*)alloc((size_t)(2 * N_NODES + 1) * sizeof(int));
    int* bucket_cursor = (int*)alloc((size_t)NB * sizeof(int));
    int* bucket_base = (int*)alloc((size_t)(NB + 1) * sizeof(int));
    f16* bpack = (f16*)alloc((size_t)2 * DIM * DIM * sizeof(f16));                 // 256 KB

    init_cursor<<<(NB + 255) / 256, 256, 0, stream>>>(bucket_cursor);

    const long TOTAL_E = 2L * NNZ;
    const int nblkA = (int)((TOTAL_E + CHUNK - 1) / CHUNK);  // 782
    bucket_scatter<<<nblkA, 256, 0, stream>>>(rows0, cols0, vals0, rows1, cols1, vals1,
                                              bucket_cursor, tmp);

    bucket_scan<<<1, 256, 0, stream>>>(bucket_cursor, bucket_base);

    bucket_sort<<<NB, 256, 0, stream>>>(tmp, bucket_cursor, bucket_base, colval, row_start2);

    wpack_kernel<<<64, 256, 0, stream>>>(w0, w1, bpack);

    gemm_mfma<<<N_NODES / 64, 256, 0, stream>>>(x, bpack, proj);

    spmm_pass<0><<<N_NODES, 256, 0, stream>>>(proj, colval, row_start2, bias, out);
    spmm_pass<1><<<N_NODES, 256, 0, stream>>>(proj, colval, row_start2, bias, out);
}

// Round 7
// 1677.716 us; speedup vs baseline: 1.0959x; 1.0959x over previous
//
#include <hip/hip_runtime.h>
#include <cstdint>

#define N_NODES 200000
#define DIM 256
#define NNZ 6400000

#define NB 782            // coarse buckets: row >> 8
#define BUCKET_CAP 17408  // 16384 expected + 8 sigma (sigma=128)
#define CHUNK 16384       // edges per block in bucket_scatter

using f16 = _Float16;
typedef __attribute__((ext_vector_type(8))) _Float16 f16x8;
typedef __attribute__((ext_vector_type(4))) _Float16 f16x4;
typedef __attribute__((ext_vector_type(4))) float f32x4;

// ---------------- init bucket cursors ----------------
__global__ void init_cursor(int* __restrict__ cursor) {
    int i = blockIdx.x * 256 + threadIdx.x;
    if (i < NB) cursor[i] = i * BUCKET_CAP;
}

// ---------------- pass A: coarse bucket scatter ----------------
// tmp record: lo32 = (col*2+adj) | (rowlocal<<19); hi32 = f32 bits of val
__global__ __launch_bounds__(256) void bucket_scatter(
    const int* __restrict__ rows0, const int* __restrict__ cols0, const float* __restrict__ vals0,
    const int* __restrict__ rows1, const int* __restrict__ cols1, const float* __restrict__ vals1,
    int* __restrict__ bucket_cursor, unsigned long long* __restrict__ tmp) {
    __shared__ int hist[NB];
    __shared__ int base[NB];
    const int t = threadIdx.x;
    const long e0 = (long)blockIdx.x * CHUNK;
    const int nE = (int)min((long)CHUNK, (long)(2 * NNZ) - e0);

    for (int i = t; i < NB; i += 256) hist[i] = 0;
    __syncthreads();

    for (int i = t; i < nE; i += 256) {
        long e = e0 + i;
        int r = (e < NNZ) ? rows0[e] : rows1[e - NNZ];
        atomicAdd(&hist[r >> 8], 1);
    }
    __syncthreads();

    for (int i = t; i < NB; i += 256) {
        int c = hist[i];
        base[i] = c ? atomicAdd(&bucket_cursor[i], c) : 0;
        hist[i] = 0;
    }
    __syncthreads();

    for (int i = t; i < nE; i += 256) {
        long e = e0 + i;
        int r, c;
        float v;
        unsigned adj;
        if (e < NNZ) {
            r = rows0[e]; c = cols0[e]; v = vals0[e]; adj = 0u;
        } else {
            long e1 = e - NNZ;
            r = rows1[e1]; c = cols1[e1]; v = vals1[e1]; adj = 1u;
        }
        int b = r >> 8;
        int pos = base[b] + atomicAdd(&hist[b], 1);
        if (pos < (b + 1) * BUCKET_CAP) {  // overflow guard (P ~ 1e-12)
            unsigned lo = ((unsigned)c * 2u + adj) | ((unsigned)(r & 255) << 19);
            tmp[pos] = (unsigned long long)lo | ((unsigned long long)__float_as_uint(v) << 32);
        }
    }
}

// ---------------- pass B: scan bucket counts ----------------
__global__ void bucket_scan(const int* __restrict__ bucket_cursor, int* __restrict__ bucket_base) {
    __shared__ int cnt[NB + 1];
    int t = threadIdx.x;
    for (int i = t; i < NB; i += 256) {
        int c = bucket_cursor[i] - i * BUCKET_CAP;
        cnt[i] = (c > BUCKET_CAP) ? BUCKET_CAP : c;
    }
    __syncthreads();
    if (t == 0) {
        int run = 0;
        for (int i = 0; i < NB; i++) {
            int c = cnt[i];
            cnt[i] = run;
            run += c;
        }
        cnt[NB] = run;
    }
    __syncthreads();
    for (int i = t; i <= NB; i += 256) bucket_base[i] = cnt[i];
}

// ---------------- pass C: per-bucket fine sort into CSR + row_start ----------------
__global__ __launch_bounds__(256) void bucket_sort(
    const unsigned long long* __restrict__ tmp, const int* __restrict__ bucket_cursor,
    const int* __restrict__ bucket_base, unsigned long long* __restrict__ colval,
    int* __restrict__ row_start) {
    __shared__ int hist[256];
    __shared__ int offs[256];
    const int b = blockIdx.x;
    const int t = threadIdx.x;
    int cnt = bucket_cursor[b] - b * BUCKET_CAP;
    if (cnt > BUCKET_CAP) cnt = BUCKET_CAP;
    const int gbase = bucket_base[b];
    const long tbase = (long)b * BUCKET_CAP;

    hist[t] = 0;
    __syncthreads();
    for (int i = t; i < cnt; i += 256) {
        unsigned lo = (unsigned)tmp[tbase + i];
        atomicAdd(&hist[(lo >> 19) & 255], 1);
    }
    __syncthreads();

    int s = hist[t];
    offs[t] = s;
    __syncthreads();
    for (int off = 1; off < 256; off <<= 1) {
        int v = (t >= off) ? offs[t - off] : 0;
        __syncthreads();
        offs[t] += v;
        __syncthreads();
    }
    int excl = offs[t] - s;  // exclusive scan

    int row = b * 256 + t;
    if (row < N_NODES) row_start[row] = gbase + excl;
    if (b == 0 && t == 0) row_start[N_NODES] = bucket_base[NB];
    __syncthreads();
    offs[t] = excl;
    hist[t] = 0;
    __syncthreads();

    for (int i = t; i < cnt; i += 256) {
        unsigned long long v = tmp[tbase + i];
        unsigned lo = (unsigned)v;
        int rl = (lo >> 19) & 255;
        int pos = gbase + offs[rl] + atomicAdd(&hist[rl], 1);
        colval[pos] = v & 0xFFFFFFFF0007FFFFULL;  // strip rowlocal bits
    }
}

// ---------------- pack W0|W1 into per-lane MFMA B-fragments ----------------
__global__ void wpack_kernel(const float* __restrict__ w0, const float* __restrict__ w1,
                             f16* __restrict__ bpack) {
    int idx = blockIdx.x * 256 + threadIdx.x;  // 16384 threads
    int lane = idx & 63;
    int ct = (idx >> 6) & 31;
    int kstep = idx >> 11;
    int col = ct * 16 + (lane & 15);
    int k0 = kstep * 32 + (lane >> 4) * 8;
    const float* w = (col < 256) ? w0 : w1;
    int c = col & 255;
    union { f16 h[8]; uint4 u; } pk;
#pragma unroll
    for (int j = 0; j < 8; j++) pk.h[j] = (f16)w[(k0 + j) * 256 + c];
    reinterpret_cast<uint4*>(bpack)[idx] = pk.u;
}

// ---------------- MFMA GEMM: proj[node][512] = f16(X @ [W0|W1]) ----------------
__global__ __launch_bounds__(256) void gemm_mfma(const float* __restrict__ x,
                                                 const f16* __restrict__ bpack,
                                                 f16* __restrict__ proj) {
    __shared__ float4 xs4[64 * 64];  // 64 KB
    const int t = threadIdx.x;
    const long r0 = (long)blockIdx.x * 64;
    const float4* xg = reinterpret_cast<const float4*>(x + r0 * 256);
#pragma unroll
    for (int i = 0; i < 16; i++) {
        int idx = t + i * 256;
        int row = idx >> 6, g = idx & 63;
        xs4[row * 64 + (g ^ (row & 7))] = xg[idx];
    }
    __syncthreads();

    const int w = t >> 6, l = t & 63;
    const int r = l & 15, q = l >> 4;
    const int lrow = w * 16 + r;
    const int s = r & 7;

    for (int half = 0; half < 2; half++) {
        f32x4 acc[16];
#pragma unroll
        for (int ct = 0; ct < 16; ct++) acc[ct] = (f32x4){0.f, 0.f, 0.f, 0.f};

        for (int kstep = 0; kstep < 8; kstep++) {
            int g0 = kstep * 8 + q * 2;
            float4 a0 = xs4[lrow * 64 + (g0 ^ s)];
            float4 a1 = xs4[lrow * 64 + ((g0 + 1) ^ s)];
            f16x8 af;
            af[0] = (f16)a0.x; af[1] = (f16)a0.y; af[2] = (f16)a0.z; af[3] = (f16)a0.w;
            af[4] = (f16)a1.x; af[5] = (f16)a1.y; af[6] = (f16)a1.z; af[7] = (f16)a1.w;
            const f16x8* bp =
                reinterpret_cast<const f16x8*>(bpack) + ((kstep * 32 + half * 16) * 64 + l);
#pragma unroll
            for (int ct = 0; ct < 16; ct++) {
                f16x8 bf = bp[ct * 64];
                acc[ct] = __builtin_amdgcn_mfma_f32_16x16x32_f16(af, bf, acc[ct], 0, 0, 0);
            }
        }
#pragma unroll
        for (int ct = 0; ct < 16; ct++) {
            int col = (half * 16 + ct) * 16 + r;
#pragma unroll
            for (int i = 0; i < 4; i++) {
                long row = r0 + w * 16 + q * 4 + i;
                proj[row * 512 + col] = (f16)acc[ct][i];
            }
        }
    }
}

// ---------------- SpMM + bias + tanh: wave-per-row, 4 f16/lane ----------------
// Block = 4 waves; wave w owns row blockIdx.x*4+w. Lane owns cols lane*4..lane*4+3.
__global__ __launch_bounds__(256) void spmm_kernel(const f16* __restrict__ proj,
                                                   const unsigned long long* __restrict__ colval,
                                                   const int* __restrict__ row_start,
                                                   const float* __restrict__ bias,
                                                   float* __restrict__ out) {
    __shared__ unsigned long long se[4][64];
    const int t = threadIdx.x;
    const int w = t >> 6;     // wave id
    const int lane = t & 63;
    const int rnode = blockIdx.x * 4 + w;

    int beg = row_start[rnode];
    const int end = row_start[rnode + 1];

    const float4 b4 = reinterpret_cast<const float4*>(bias)[lane];
    float a0 = b4.x, a1 = b4.y, a2 = b4.z, a3 = b4.w;

    const char* projb = reinterpret_cast<const char*>(proj);
    const unsigned laneoff = (unsigned)lane << 3;  // byte offset of 4 f16 within 512B row

    while (beg < end) {
        int chunk = min(64, end - beg);
        if (lane < chunk) se[w][lane] = colval[beg + lane];
        __builtin_amdgcn_wave_barrier();
        int j = 0;
        for (; j + 8 <= chunk; j += 8) {
#pragma unroll
            for (int jj = 0; jj < 8; jj++) {
                unsigned long long e = se[w][j + jj];
                unsigned boff = ((unsigned)(e & 0x7FFFFu) << 9) | laneoff;
                f16x4 pv = *reinterpret_cast<const f16x4*>(projb + boff);
                float val = __uint_as_float((unsigned)(e >> 32));
                a0 = fmaf(val, (float)pv[0], a0);
                a1 = fmaf(val, (float)pv[1], a1);
                a2 = fmaf(val, (float)pv[2], a2);
                a3 = fmaf(val, (float)pv[3], a3);
            }
        }
        for (; j < chunk; j++) {
            unsigned long long e = se[w][j];
            unsigned boff = ((unsigned)(e & 0x7FFFFu) << 9) | laneoff;
            f16x4 pv = *reinterpret_cast<const f16x4*>(projb + boff);
            float val = __uint_as_float((unsigned)(e >> 32));
            a0 = fmaf(val, (float)pv[0], a0);
            a1 = fmaf(val, (float)pv[1], a1);
            a2 = fmaf(val, (float)pv[2], a2);
            a3 = fmaf(val, (float)pv[3], a3);
        }
        beg += chunk;
        __builtin_amdgcn_wave_barrier();
    }

    f32x4 res = {tanhf(a0), tanhf(a1), tanhf(a2), tanhf(a3)};
    __builtin_nontemporal_store(res, reinterpret_cast<f32x4*>(out + (long)rnode * 256) + lane);
}

extern "C" void kernel_launch(void* const* d_in, const int* in_sizes, int n_in,
                              void* d_out, int out_size, void* d_ws, size_t ws_size,
                              hipStream_t stream) {
    const float* x = (const float*)d_in[0];
    const float* w0 = (const float*)d_in[1];
    const float* w1 = (const float*)d_in[2];
    const float* bias = (const float*)d_in[3];
    const float* vals0 = (const float*)d_in[4];
    const float* vals1 = (const float*)d_in[5];
    const int* rows0 = (const int*)d_in[6];
    const int* cols0 = (const int*)d_in[7];
    const int* rows1 = (const int*)d_in[8];
    const int* cols1 = (const int*)d_in[9];
    float* out = (float*)d_out;

    char* ws = (char*)d_ws;
    size_t off = 0;
    auto alloc = [&](size_t bytes) -> void* {
        void* p = ws + off;
        off += (bytes + 255) & ~(size_t)255;
        return p;
    };
    unsigned long long* colval =
        (unsigned long long*)alloc((size_t)2 * NNZ * sizeof(unsigned long long));  // 102.4 MB
    // proj (205 MB) aliases tmp (109 MB): tmp is dead before gemm_mfma runs
    char* shared_region = (char*)alloc((size_t)N_NODES * 512 * sizeof(f16));       // 204.8 MB
    f16* proj = (f16*)shared_region;
    unsigned long long* tmp = (unsigned long long*)shared_region;
    int* row_start = (int*)alloc((size_t)(N_NODES + 1) * sizeof(int));
    int* bucket_cursor = (int*)alloc((size_t)NB * sizeof(int));
    int* bucket_base = (int*)alloc((size_t)(NB + 1) * sizeof(int));
    f16* bpack = (f16*)alloc((size_t)2 * DIM * DIM * sizeof(f16));                 // 256 KB

    init_cursor<<<(NB + 255) / 256, 256, 0, stream>>>(bucket_cursor);

    const long TOTAL_E = 2L * NNZ;
    const int nblkA = (int)((TOTAL_E + CHUNK - 1) / CHUNK);  // 782
    bucket_scatter<<<nblkA, 256, 0, stream>>>(rows0, cols0, vals0, rows1, cols1, vals1,
                                              bucket_cursor, tmp);

    bucket_scan<<<1, 256, 0, stream>>>(bucket_cursor, bucket_base);

    bucket_sort<<<NB, 256, 0, stream>>>(tmp, bucket_cursor, bucket_base, colval, row_start);

    wpack_kernel<<<64, 256, 0, stream>>>(w0, w1, bpack);

    gemm_mfma<<<N_NODES / 64, 256, 0, stream>>>(x, bpack, proj);

    spmm_kernel<<<N_NODES / 4, 256, 0, stream>>>(proj, colval, row_start, bias, out);
}